// Round 1
// baseline (578.887 us; speedup 1.0000x reference)
//
#include <hip/hip_runtime.h>

#define Bz 256
#define Sz 64
#define Hz 256
#define Vz 32000
#define Tz 11
#define Mz (Bz*Tz)   // 2816

typedef __attribute__((ext_vector_type(8))) short bf16x8;
typedef __attribute__((ext_vector_type(4))) float f32x4;

__device__ __forceinline__ float blo(unsigned int u){ return __builtin_bit_cast(float, u<<16); }
__device__ __forceinline__ float bhi(unsigned int u){ return __builtin_bit_cast(float, u & 0xffff0000u); }
__device__ __forceinline__ unsigned short f2bf(float f){
  unsigned int x = __builtin_bit_cast(unsigned int, f);
  return (unsigned short)((x + 0x7fffu + ((x>>16)&1u)) >> 16);
}
__device__ __forceinline__ float bf2f(unsigned short u){ return __builtin_bit_cast(float, ((unsigned int)u)<<16); }
__device__ __forceinline__ float ftanh(float x){ float e = __expf(2.f*x); return 1.f - 2.f/(e+1.f); }

__device__ __forceinline__ float dot8(uint4 wv, const float* base){
  float4 h0 = *(const float4*)(base);
  float4 h1 = *(const float4*)(base+4);
  return blo(wv.x)*h0.x + bhi(wv.x)*h0.y + blo(wv.y)*h0.z + bhi(wv.y)*h0.w
       + blo(wv.z)*h1.x + bhi(wv.z)*h1.y + blo(wv.w)*h1.z + bhi(wv.w)*h1.w;
}

// ---------------- P3: convert weights to bf16 ----------------
__global__ __launch_bounds__(256) void k_convert(
    const float* __restrict__ Wout, const float* __restrict__ Wa,
    const float* __restrict__ Wih, const float* __restrict__ Whh,
    unsigned short* __restrict__ wout_b, unsigned short* __restrict__ wa_b,
    unsigned short* __restrict__ wih2_b, unsigned short* __restrict__ whh_b){
  int i = blockIdx.x*256 + threadIdx.x;
  int stride = gridDim.x*256;
  for (int idx = i; idx < Vz*Hz; idx += stride) wout_b[idx] = f2bf(Wout[idx]);
  for (int idx = i; idx < Hz*Hz; idx += stride){
    wa_b[idx]  = f2bf(Wa[idx]);
    whh_b[idx] = f2bf(Whh[idx]);
    int k = idx>>8, j = idx&255;
    wih2_b[idx] = f2bf(Wih[k*512 + 256 + j]);
  }
}

// ---------------- P1: E[m][k] = b_ih[k] + emb(tok_m) . W_ih[k][0:256] ----------------
__global__ __launch_bounds__(256) void k_emb_gemv(
    const int* __restrict__ target, const float* __restrict__ embedding,
    const float* __restrict__ Wih, const float* __restrict__ b_ih,
    float* __restrict__ E){
  __shared__ float emb_lds[16][Hz];
  int tid = threadIdx.x;
  int m0 = blockIdx.x*16;
  for (int r=0;r<16;r++){
    int m = m0 + r; int b = m/11, t = m - b*11;
    int tok = (t==0) ? 0 : target[b*11 + (t-1)];
    emb_lds[r][tid] = embedding[(size_t)tok*Hz + tid];
  }
  __syncthreads();
  float acc[16];
  #pragma unroll
  for (int r=0;r<16;r++) acc[r]=0.f;
  const float* wrow = Wih + tid*512;   // W_ih row k, first 256 cols
  for (int j4=0;j4<64;j4++){
    float4 w = *(const float4*)(wrow + j4*4);
    #pragma unroll
    for (int r=0;r<16;r++){
      float4 e = *(const float4*)(&emb_lds[r][j4*4]);
      acc[r] += w.x*e.x + w.y*e.y + w.z*e.z + w.w*e.w;
    }
  }
  float bi = b_ih[tid];
  for (int r=0;r<16;r++) E[(m0+r)*Hz + tid] = acc[r] + bi;
}

// ---------------- P2: uk[b,s,k] = bua[k] + enc[b,s,:] . Ua[k,:]  (bf16 out) ----------------
__global__ __launch_bounds__(256) void k_uk(
    const float* __restrict__ enc, const float* __restrict__ Ua,
    const float* __restrict__ bua, unsigned short* __restrict__ uk_b){
  __shared__ float rows[16][Hz];
  int tid = threadIdx.x;
  int r0 = blockIdx.x*16;
  for (int r=0;r<16;r++) rows[r][tid] = enc[(size_t)(r0+r)*Hz + tid];
  __syncthreads();
  float acc[16];
  #pragma unroll
  for (int r=0;r<16;r++) acc[r]=0.f;
  const float* wrow = Ua + tid*Hz;
  for (int j4=0;j4<64;j4++){
    float4 w = *(const float4*)(wrow + j4*4);
    #pragma unroll
    for (int r=0;r<16;r++){
      float4 e = *(const float4*)(&rows[r][j4*4]);
      acc[r] += w.x*e.x + w.y*e.y + w.z*e.z + w.w*e.w;
    }
  }
  float bk = bua[tid];
  for (int r=0;r<16;r++) uk_b[(size_t)(r0+r)*Hz + tid] = f2bf(acc[r] + bk);
}

// ---------------- recurrence: one block per batch element, loops 11 steps ----------------
__global__ __launch_bounds__(256) void k_rnn(
    const float* __restrict__ enc, const float* __restrict__ ench,
    const float* __restrict__ ba, const float* __restrict__ Va,
    const float* __restrict__ bva, const float* __restrict__ b_hh,
    const unsigned short* __restrict__ uk_b, const unsigned short* __restrict__ wa_b,
    const unsigned short* __restrict__ wih2_b, const unsigned short* __restrict__ whh_b,
    const float* __restrict__ E, unsigned short* __restrict__ hs_b,
    float* __restrict__ out_hlast, float* __restrict__ out_attn){
  __shared__ __align__(16) unsigned short uk_lds[Sz][Hz];  // 32KB
  __shared__ __align__(16) float h_lds[Hz];
  __shared__ __align__(16) float q_lds[Hz];
  __shared__ __align__(16) float ctx_lds[Hz];
  __shared__ float sc_lds[Sz];
  __shared__ float attn_lds[Sz];
  int b = blockIdx.x, tid = threadIdx.x;
  int lane = tid & 63, w = tid >> 6;

  { // stage uk[b] (bf16, 32KB) into LDS
    const uint4* src = (const uint4*)(uk_b + (size_t)b*Sz*Hz);
    uint4* dst = (uint4*)(&uk_lds[0][0]);
    #pragma unroll
    for (int i=0;i<8;i++) dst[i*256+tid] = src[i*256+tid];
  }
  h_lds[tid] = ench[b*Hz + tid];
  float va_r[4];
  #pragma unroll
  for (int c=0;c<4;c++) va_r[c] = Va[lane + 64*c];
  float ba_k = ba[tid], bhh_k = b_hh[tid], bva_s = bva[0];
  const float* encb = enc + (size_t)b*Sz*Hz;
  __syncthreads();

  for (int t=0; t<Tz; t++){
    int m = b*Tz + t;
    // ---- q[k] = ba[k] + h . Wa[k,:]
    {
      float qa = ba_k;
      const uint4* war = (const uint4*)(wa_b + tid*Hz);
      #pragma unroll 4
      for (int j8=0;j8<32;j8++) qa += dot8(war[j8], &h_lds[j8*8]);
      q_lds[tid] = qa;
    }
    __syncthreads();
    // ---- scores[s] = sum_k tanh(q[k]+uk[s][k]) * Va[k] + bva ; wave w handles 16 s
    {
      float ql[4];
      #pragma unroll
      for (int c=0;c<4;c++) ql[c] = q_lds[lane + 64*c];
      for (int si=0; si<16; si++){
        int s = w*16 + si;
        float p = 0.f;
        #pragma unroll
        for (int c=0;c<4;c++){
          float u = bf2f(uk_lds[s][lane + 64*c]);
          p += ftanh(ql[c] + u) * va_r[c];
        }
        #pragma unroll
        for (int off=1; off<64; off<<=1) p += __shfl_xor(p, off, 64);
        if (lane==0) sc_lds[s] = p + bva_s;
      }
    }
    __syncthreads();
    // ---- softmax over s (redundant per thread; cheap)
    {
      float mx = -1e30f;
      for (int s=0;s<Sz;s++) mx = fmaxf(mx, sc_lds[s]);
      float sum = 0.f;
      for (int s=0;s<Sz;s++) sum += __expf(sc_lds[s]-mx);
      float inv = 1.f/sum;
      if (tid < Sz){
        float a = __expf(sc_lds[tid]-mx)*inv;
        attn_lds[tid] = a;
        out_attn[(size_t)m*Sz + tid] = a;
      }
    }
    __syncthreads();
    // ---- ctx[k] = sum_s attn[s]*enc[b,s,k]
    {
      float cacc = 0.f;
      for (int s=0;s<Sz;s++) cacc += attn_lds[s]*encb[s*Hz+tid];
      ctx_lds[tid] = cacc;
    }
    __syncthreads();
    // ---- h_new[k] = tanh(E[m,k] + b_hh[k] + ctx.Wih2[k,:] + h.Whh[k,:])
    float hn;
    {
      float acc = E[(size_t)m*Hz+tid] + bhh_k;
      const uint4* w2 = (const uint4*)(wih2_b + tid*Hz);
      const uint4* wh = (const uint4*)(whh_b + tid*Hz);
      #pragma unroll 4
      for (int j8=0;j8<32;j8++){
        acc += dot8(w2[j8], &ctx_lds[j8*8]);
        acc += dot8(wh[j8], &h_lds[j8*8]);
      }
      hn = ftanh(acc);
    }
    __syncthreads();          // everyone done reading h_lds
    h_lds[tid] = hn;
    hs_b[(size_t)m*Hz + tid] = f2bf(hn);
    if (t==Tz-1) out_hlast[b*Hz + tid] = hn;
    __syncthreads();
  }
}

// ---------------- big GEMM: C[m][v] = hs[m,:].Wout[v,:] + b_out[v] ----------------
// lse==nullptr: pass1 -> write per-(row, nblock, wn) partial sum(exp(logit))
// lse!=nullptr: pass2 -> write out = logit - lse[row]
__global__ __launch_bounds__(256) void k_gemm(
    const unsigned short* __restrict__ Ab, const unsigned short* __restrict__ Bb,
    const float* __restrict__ b_out, const float* __restrict__ lse,
    float* __restrict__ out, float* __restrict__ partials){
  __shared__ __align__(16) unsigned short As[128*64];
  __shared__ __align__(16) unsigned short Bs[128*64];
  int tid = threadIdx.x;
  int bn = blockIdx.x;        // 0..249
  int bm = blockIdx.y;        // 0..21
  int m0 = bm*128, n0 = bn*128;
  int w = tid>>6, lane = tid&63;
  int wm = w>>1, wn = w&1;
  f32x4 acc[4][4];
  #pragma unroll
  for (int i=0;i<4;i++)
    #pragma unroll
    for (int j=0;j<4;j++) acc[i][j] = (f32x4){0.f,0.f,0.f,0.f};

  for (int kt=0; kt<4; kt++){
    __syncthreads();
    #pragma unroll
    for (int i=0;i<4;i++){
      int chunk = i*256 + tid;          // 0..1023
      int row = chunk>>3, c8 = chunk&7;
      *(uint4*)(&As[chunk*8]) = *(const uint4*)(Ab + (size_t)(m0+row)*Hz + kt*64 + c8*8);
      *(uint4*)(&Bs[chunk*8]) = *(const uint4*)(Bb + (size_t)(n0+row)*Hz + kt*64 + c8*8);
    }
    __syncthreads();
    #pragma unroll
    for (int ks=0; ks<2; ks++){
      bf16x8 af[4], bg[4];
      #pragma unroll
      for (int i=0;i<4;i++){
        int row = wm*64 + i*16 + (lane&15);
        af[i] = *(const bf16x8*)(&As[row*64 + ks*32 + (lane>>4)*8]);
      }
      #pragma unroll
      for (int j=0;j<4;j++){
        int row = wn*64 + j*16 + (lane&15);
        bg[j] = *(const bf16x8*)(&Bs[row*64 + ks*32 + (lane>>4)*8]);
      }
      #pragma unroll
      for (int i=0;i<4;i++)
        #pragma unroll
        for (int j=0;j<4;j++)
          acc[i][j] = __builtin_amdgcn_mfma_f32_16x16x32_bf16(af[i], bg[j], acc[i][j], 0,0,0);
    }
  }
  int col_l = lane & 15, rgrp = lane >> 4;
  if (lse == nullptr){
    #pragma unroll
    for (int i=0;i<4;i++){
      int rowbase = m0 + wm*64 + i*16 + rgrp*4;
      #pragma unroll
      for (int r=0;r<4;r++){
        float se = 0.f;
        #pragma unroll
        for (int j=0;j<4;j++){
          int col = n0 + wn*64 + j*16 + col_l;
          se += __expf(acc[i][j][r] + b_out[col]);
        }
        se += __shfl_xor(se,1,64); se += __shfl_xor(se,2,64);
        se += __shfl_xor(se,4,64); se += __shfl_xor(se,8,64);
        if (col_l == 0) partials[(size_t)(rowbase+r)*500 + bn*2 + wn] = se;
      }
    }
  } else {
    #pragma unroll
    for (int i=0;i<4;i++){
      int rowbase = m0 + wm*64 + i*16 + rgrp*4;
      #pragma unroll
      for (int r=0;r<4;r++){
        float l = lse[rowbase + r];
        #pragma unroll
        for (int j=0;j<4;j++){
          int col = n0 + wn*64 + j*16 + col_l;
          out[(size_t)(rowbase+r)*Vz + col] = acc[i][j][r] + b_out[col] - l;
        }
      }
    }
  }
}

__global__ __launch_bounds__(256) void k_lse(const float* __restrict__ partials,
                                             float* __restrict__ lse){
  int m = blockIdx.x*256 + threadIdx.x;
  if (m < Mz){
    float s = 0.f;
    for (int c=0;c<500;c++) s += partials[(size_t)m*500+c];
    lse[m] = logf(s);
  }
}

extern "C" void kernel_launch(void* const* d_in, const int* in_sizes, int n_in,
                              void* d_out, int out_size, void* d_ws, size_t ws_size,
                              hipStream_t stream) {
  const float* enc   = (const float*)d_in[0];
  const float* ench  = (const float*)d_in[1];
  const int*   target= (const int*)d_in[2];
  const float* emb   = (const float*)d_in[3];
  const float* Wa    = (const float*)d_in[4];
  const float* ba    = (const float*)d_in[5];
  const float* Ua    = (const float*)d_in[6];
  const float* bua   = (const float*)d_in[7];
  const float* Va    = (const float*)d_in[8];
  const float* bva   = (const float*)d_in[9];
  const float* Wih   = (const float*)d_in[10];
  const float* bih   = (const float*)d_in[11];
  const float* Whh   = (const float*)d_in[12];
  const float* bhh   = (const float*)d_in[13];
  const float* Wout  = (const float*)d_in[14];
  const float* bout  = (const float*)d_in[15];

  float* out = (float*)d_out;
  float* out_logits = out;                              // [2816][32000]
  float* out_hlast  = out + (size_t)Mz*Vz;              // [256][256]
  float* out_attn   = out_hlast + Bz*Hz;                // [2816][64]

  // ws layout (needs ~18.3 MB): bf16 W_out + small bf16 weights + hs + lse
  char* ws = (char*)d_ws;
  unsigned short* wout_b = (unsigned short*)(ws);                 // 16,384,000 B
  unsigned short* wa_b   = (unsigned short*)(ws + 16384000);      // 131,072
  unsigned short* wih2_b = (unsigned short*)(ws + 16515072);      // 131,072
  unsigned short* whh_b  = (unsigned short*)(ws + 16646144);      // 131,072
  unsigned short* hs_b   = (unsigned short*)(ws + 16777216);      // 1,441,792
  float*          lse    = (float*)(ws + 18219008);               // 11,264

  // bulky transients live in the (not-yet-written) logits region of d_out:
  // uk (8,388,608 B) | E (2,883,584 B) | partials (5,632,000 B) — all dead before pass-2 writes
  char* sc = (char*)d_out;
  unsigned short* uk_b     = (unsigned short*)(sc);
  float*          E        = (float*)(sc + 8388608);
  float*          partials = (float*)(sc + 11272192);

  k_convert <<<2048, 256, 0, stream>>>(Wout, Wa, Wih, Whh, wout_b, wa_b, wih2_b, whh_b);
  k_emb_gemv<<<176, 256, 0, stream>>>(target, emb, Wih, bih, E);
  k_uk      <<<1024, 256, 0, stream>>>(enc, Ua, bua, uk_b);
  k_rnn     <<<256, 256, 0, stream>>>(enc, ench, ba, Va, bva, bhh,
                                      uk_b, wa_b, wih2_b, whh_b, E, hs_b,
                                      out_hlast, out_attn);
  k_gemm    <<<dim3(250,22), 256, 0, stream>>>(hs_b, wout_b, bout, nullptr, out_logits, partials);
  k_lse     <<<11, 256, 0, stream>>>(partials, lse);
  k_gemm    <<<dim3(250,22), 256, 0, stream>>>(hs_b, wout_b, bout, lse, out_logits, partials);
}